// Round 3
// baseline (197.536 us; speedup 1.0000x reference)
//
#include <hip/hip_runtime.h>
#include <hip/hip_bf16.h>
#include <math.h>

#define EMB 1024
#define HEAD 64
#define NB 4
#define SEQ 4096
#define MTOT (NB * SEQ)
// fold 1/sqrt(64) and log2(e) into Q so softmax runs in base-2 (v_exp_f32 native)
#define QSCALE (0.125f * 1.44269504088896f)

typedef __attribute__((ext_vector_type(8))) short bf16x8;
typedef __attribute__((ext_vector_type(4))) float f32x4;

static __device__ __forceinline__ unsigned short f2b(float f) {
    union { float f; unsigned u; } v; v.f = f;
    unsigned r = v.u + 0x7FFFu + ((v.u >> 16) & 1u);
    return (unsigned short)(r >> 16);
}
static __device__ __forceinline__ float b2f(unsigned short u) {
    union { unsigned u; float f; } v; v.u = ((unsigned)u) << 16; return v.f;
}
// packed f32x2 -> bf16x2 (RTNE), one instruction
static __device__ __forceinline__ unsigned pk2(float lo, float hi) {
    unsigned r;
    asm("v_cvt_pk_bf16_f32 %0, %1, %2" : "=v"(r) : "v"(lo), "v"(hi));
    return r;
}

// ---------------------------------------------------------------------------
// Kernel 1: W transpose + bf16 cast.  Wt layout: [3][64 n][1024 k]
// ---------------------------------------------------------------------------
__global__ void wt_kernel(const float* __restrict__ Wq, const float* __restrict__ Wk,
                          const float* __restrict__ Wv, unsigned short* __restrict__ Wt) {
    const int idx = blockIdx.x * 256 + threadIdx.x;   // 3*64*1024 = 196608
    const int m = idx >> 16;
    const int r = idx & 65535;
    const int n = r >> 10, k = r & 1023;
    const float* W = (m == 0) ? Wq : (m == 1) ? Wk : Wv;
    Wt[idx] = f2b(W[k * HEAD + n]);
}

// ---------------------------------------------------------------------------
// Kernel 2: fused QKV projection, BARRIER-FREE (no LDS). grid MTOT/32 = 512,
// 256 threads = 4 waves; wave w owns cols w*48..w*48+47 (3 n-frags) x 32 rows
// (2 m-frags). A-frags straight from global x (fp32 -> packed bf16 cvt),
// B-frags from Wt (L2-resident). x read once (64 MB).
// ---------------------------------------------------------------------------
__global__ __launch_bounds__(256, 4) void proj_kernel(
    const float* __restrict__ x, const unsigned short* __restrict__ Wt3,
    const float* __restrict__ bq, const float* __restrict__ bk,
    const float* __restrict__ bv, unsigned short* __restrict__ qg,
    unsigned short* __restrict__ kg, unsigned short* __restrict__ vt) {
    const int tid = threadIdx.x;
    const int cg = tid >> 6, lane = tid & 63;
    const int li = lane & 15, lg = lane >> 4;
    const int rbase = blockIdx.x * 32;

    f32x4 acc[2][3];
#pragma unroll
    for (int m = 0; m < 2; ++m)
#pragma unroll
        for (int n = 0; n < 3; ++n) acc[m][n] = (f32x4){0.f, 0.f, 0.f, 0.f};

    const float* xp0 = x + (size_t)(rbase + li) * EMB + lg * 8;
    const float* xp1 = x + (size_t)(rbase + 16 + li) * EMB + lg * 8;
    const unsigned short* wp0 = Wt3 + (size_t)(cg * 48 + li) * EMB + lg * 8;

#pragma unroll 2
    for (int k0 = 0; k0 < EMB; k0 += 64) {
        bf16x8 a[2][2];
#pragma unroll
        for (int m = 0; m < 2; ++m) {
            const float* xp = (m == 0 ? xp0 : xp1) + k0;
            const float4 t0 = *(const float4*)(xp);
            const float4 t1 = *(const float4*)(xp + 4);
            const float4 t2 = *(const float4*)(xp + 32);
            const float4 t3 = *(const float4*)(xp + 36);
            union { bf16x8 v; unsigned u[4]; } a0, a1;
            a0.u[0] = pk2(t0.x, t0.y); a0.u[1] = pk2(t0.z, t0.w);
            a0.u[2] = pk2(t1.x, t1.y); a0.u[3] = pk2(t1.z, t1.w);
            a1.u[0] = pk2(t2.x, t2.y); a1.u[1] = pk2(t2.z, t2.w);
            a1.u[2] = pk2(t3.x, t3.y); a1.u[3] = pk2(t3.z, t3.w);
            a[m][0] = a0.v; a[m][1] = a1.v;
        }
        bf16x8 b[3][2];
#pragma unroll
        for (int n = 0; n < 3; ++n) {
            const unsigned short* wp = wp0 + n * 16 * EMB + k0;
            b[n][0] = *(const bf16x8*)(wp);
            b[n][1] = *(const bf16x8*)(wp + 32);
        }
#pragma unroll
        for (int m = 0; m < 2; ++m)
#pragma unroll
            for (int n = 0; n < 3; ++n) {
                acc[m][n] = __builtin_amdgcn_mfma_f32_16x16x32_bf16(a[m][0], b[n][0], acc[m][n], 0, 0, 0);
                acc[m][n] = __builtin_amdgcn_mfma_f32_16x16x32_bf16(a[m][1], b[n][1], acc[m][n], 0, 0, 0);
            }
    }
    // epilogue: frag f = cg*3+n -> mat = f>>2, col16 = (f&3)*16
#pragma unroll
    for (int m = 0; m < 2; ++m)
#pragma unroll
        for (int n = 0; n < 3; ++n) {
            const int f = cg * 3 + n;
            const int mat = f >> 2;
            const int nc = (f & 3) * 16 + li;
            const float bb = (mat == 0) ? bq[nc] : (mat == 1) ? bk[nc] : bv[nc];
#pragma unroll
            for (int r = 0; r < 4; ++r) {
                const int grow = rbase + m * 16 + lg * 4 + r;
                const float val = acc[m][n][r] + bb;
                if (mat == 0) {
                    qg[(size_t)grow * HEAD + nc] = f2b(val * QSCALE);
                } else if (mat == 1) {
                    kg[(size_t)grow * HEAD + nc] = f2b(val);
                } else {
                    const int bi = grow >> 12, si = grow & 4095;
                    vt[((size_t)bi * HEAD + nc) * SEQ + si] = f2b(val);
                }
            }
        }
}

// ---------------------------------------------------------------------------
// Kernel 3: flash attention (causal). grid (128, NB) x 512 threads = 8 waves.
// Block owns a 32-row q-tile; wave w takes KV tiles t = w, w+8, ... (KVBLK=64).
// All 4096 waves resident (4/SIMD). Per-lane partial l (no in-loop sum tree),
// defer-max rescale, packed bf16 cvt for P. 8-way partial merge at end.
// ---------------------------------------------------------------------------
__global__ __launch_bounds__(512, 4) void attn_kernel(
    const unsigned short* __restrict__ Qg, const unsigned short* __restrict__ Kg,
    const unsigned short* __restrict__ Vtg, float* __restrict__ out) {
    // per-wave 4608B: P tile [2][16][72] during loop, O-partial [32][72] after.
    __shared__ unsigned short U[8][2304];
    __shared__ float ml[8][32][2];

    const int tid = threadIdx.x, w = tid >> 6, lane = tid & 63;
    const int li = lane & 15, lg = lane >> 4;
    const int b = blockIdx.y;
    const int qa0 = blockIdx.x * 32;
    const size_t qb = (size_t)b * SEQ * HEAD;
    const unsigned short* vb = Vtg + (size_t)b * HEAD * SEQ;

    const bf16x8 qf00 = *(const bf16x8*)(Qg + qb + (size_t)(qa0 + li) * HEAD + lg * 8);
    const bf16x8 qf01 = *(const bf16x8*)(Qg + qb + (size_t)(qa0 + li) * HEAD + 32 + lg * 8);
    const bf16x8 qf10 = *(const bf16x8*)(Qg + qb + (size_t)(qa0 + 16 + li) * HEAD + lg * 8);
    const bf16x8 qf11 = *(const bf16x8*)(Qg + qb + (size_t)(qa0 + 16 + li) * HEAD + 32 + lg * 8);

    f32x4 oa[2][4];
    float mS[2][4], lS[2][4];
#pragma unroll
    for (int q = 0; q < 2; ++q)
#pragma unroll
        for (int n = 0; n < 4; ++n) oa[q][n] = (f32x4){0.f, 0.f, 0.f, 0.f};
#pragma unroll
    for (int q = 0; q < 2; ++q)
#pragma unroll
        for (int r = 0; r < 4; ++r) { mS[q][r] = -1e30f; lS[q][r] = 0.f; }

    unsigned short* Pw = U[w];
    const int ntiles = (qa0 + 95) >> 6;            // ceil((qa0+32)/64)

    for (int t = w; t < ntiles; t += 8) {
        const int kv0 = t * 64;
        bf16x8 kf[4][2], vf[4][2];
#pragma unroll
        for (int n = 0; n < 4; ++n) {
            const unsigned short* kp = Kg + qb + (size_t)(kv0 + n * 16 + li) * HEAD + lg * 8;
            kf[n][0] = *(const bf16x8*)kp;
            kf[n][1] = *(const bf16x8*)(kp + 32);
            const unsigned short* vp = vb + (size_t)(n * 16 + li) * SEQ + kv0 + lg * 8;
            vf[n][0] = *(const bf16x8*)vp;
            vf[n][1] = *(const bf16x8*)(vp + 32);
        }
        // S = Q K^T
        f32x4 s[2][4];
#pragma unroll
        for (int n = 0; n < 4; ++n) {
            f32x4 z0 = (f32x4){0.f, 0.f, 0.f, 0.f};
            f32x4 z1 = (f32x4){0.f, 0.f, 0.f, 0.f};
            z0 = __builtin_amdgcn_mfma_f32_16x16x32_bf16(qf00, kf[n][0], z0, 0, 0, 0);
            s[0][n] = __builtin_amdgcn_mfma_f32_16x16x32_bf16(qf01, kf[n][1], z0, 0, 0, 0);
            z1 = __builtin_amdgcn_mfma_f32_16x16x32_bf16(qf10, kf[n][0], z1, 0, 0, 0);
            s[1][n] = __builtin_amdgcn_mfma_f32_16x16x32_bf16(qf11, kf[n][1], z1, 0, 0, 0);
        }
        // causal mask (only the diagonal-straddling tile)
        if (kv0 + 63 > qa0) {
#pragma unroll
            for (int n = 0; n < 4; ++n) {
                const int kv = kv0 + n * 16 + li;
#pragma unroll
                for (int q = 0; q < 2; ++q) {
                    const int qq = qa0 + q * 16 + lg * 4;
#pragma unroll
                    for (int r = 0; r < 4; ++r)
                        if (kv > qq + r) s[q][n][r] = -1e30f;
                }
            }
        }
        // online softmax (base-2); per-lane partial l, defer-max rescale
#pragma unroll
        for (int q = 0; q < 2; ++q) {
            float cm[4];
#pragma unroll
            for (int r = 0; r < 4; ++r)
                cm[r] = fmaxf(fmaxf(fmaxf(s[q][0][r], s[q][1][r]), s[q][2][r]), s[q][3][r]);
#pragma unroll
            for (int off = 1; off < 16; off <<= 1)
#pragma unroll
                for (int r = 0; r < 4; ++r)
                    cm[r] = fmaxf(cm[r], __shfl_xor(cm[r], off));
            float d = -1e30f;
#pragma unroll
            for (int r = 0; r < 4; ++r) d = fmaxf(d, cm[r] - mS[q][r]);
            if (!__all(d <= 8.0f)) {
#pragma unroll
                for (int r = 0; r < 4; ++r) {
                    const float mn = fmaxf(mS[q][r], cm[r]);
                    const float sc = exp2f(mS[q][r] - mn);
                    mS[q][r] = mn;
                    lS[q][r] *= sc;
#pragma unroll
                    for (int n = 0; n < 4; ++n) oa[q][n][r] *= sc;
                }
            }
#pragma unroll
            for (int n = 0; n < 4; ++n)
#pragma unroll
                for (int r = 0; r < 4; ++r) {
                    const float p = exp2f(s[q][n][r] - mS[q][r]);
                    s[q][n][r] = p;
                    lS[q][r] += p;
                }
            // P -> wave-local LDS (packed bf16 cvt)
#pragma unroll
            for (int n = 0; n < 4; ++n) {
                const unsigned u01 = pk2(s[q][n][0], s[q][n][1]);
                const unsigned u23 = pk2(s[q][n][2], s[q][n][3]);
                unsigned short* pp = &Pw[q * 1152 + (lg * 4) * 72 + n * 16 + li];
                pp[0] = (unsigned short)u01;
                pp[72] = (unsigned short)(u01 >> 16);
                pp[144] = (unsigned short)u23;
                pp[216] = (unsigned short)(u23 >> 16);
            }
        }
        // PV
#pragma unroll
        for (int q = 0; q < 2; ++q) {
            const bf16x8 pf0 = *(const bf16x8*)&Pw[q * 1152 + li * 72 + lg * 8];
            const bf16x8 pf1 = *(const bf16x8*)&Pw[q * 1152 + li * 72 + 32 + lg * 8];
#pragma unroll
            for (int n = 0; n < 4; ++n) {
                oa[q][n] = __builtin_amdgcn_mfma_f32_16x16x32_bf16(pf0, vf[n][0], oa[q][n], 0, 0, 0);
                oa[q][n] = __builtin_amdgcn_mfma_f32_16x16x32_bf16(pf1, vf[n][1], oa[q][n], 0, 0, 0);
            }
        }
    }

    // reduce per-lane l partials across the 16-lane row groups (once)
#pragma unroll
    for (int off = 1; off < 16; off <<= 1)
#pragma unroll
        for (int q = 0; q < 2; ++q)
#pragma unroll
            for (int r = 0; r < 4; ++r)
                lS[q][r] += __shfl_xor(lS[q][r], off);

    // publish partials: O (bf16, reuse Pw region) + (m,l)
#pragma unroll
    for (int q = 0; q < 2; ++q)
#pragma unroll
        for (int n = 0; n < 4; ++n)
#pragma unroll
            for (int r = 0; r < 4; ++r)
                Pw[(q * 16 + lg * 4 + r) * 72 + n * 16 + li] = f2b(oa[q][n][r]);
    if (li == 0) {
#pragma unroll
        for (int q = 0; q < 2; ++q)
#pragma unroll
            for (int r = 0; r < 4; ++r) {
                ml[w][q * 16 + lg * 4 + r][0] = mS[q][r];
                ml[w][q * 16 + lg * 4 + r][1] = lS[q][r];
            }
    }
    __syncthreads();

    // merge 8 partials; wave w handles rows w*4..w*4+3, col = lane
#pragma unroll
    for (int rr = 0; rr < 4; ++rr) {
        const int row = w * 4 + rr;
        float ms = -1e30f;
#pragma unroll
        for (int j = 0; j < 8; ++j) ms = fmaxf(ms, ml[j][row][0]);
        float ls = 0.f, o = 0.f;
#pragma unroll
        for (int j = 0; j < 8; ++j) {
            const float c = exp2f(ml[j][row][0] - ms);
            ls += c * ml[j][row][1];
            o += c * b2f(U[j][row * 72 + lane]);
        }
        out[((size_t)b * SEQ + qa0 + row) * HEAD + lane] = o / ls;
    }
}

// ---------------------------------------------------------------------------
extern "C" void kernel_launch(void* const* d_in, const int* in_sizes, int n_in,
                              void* d_out, int out_size, void* d_ws, size_t ws_size,
                              hipStream_t stream) {
    const float* x  = (const float*)d_in[0];
    const float* Wq = (const float*)d_in[1];
    const float* bq = (const float*)d_in[2];
    const float* Wk = (const float*)d_in[3];
    const float* bk = (const float*)d_in[4];
    const float* Wv = (const float*)d_in[5];
    const float* bv = (const float*)d_in[6];

    unsigned short* Wt = (unsigned short*)d_ws;          // 3*64*1024
    unsigned short* qg = Wt + 3 * HEAD * EMB;            // MTOT*64 bf16 (Q, pre-scaled)
    unsigned short* kg = qg + (size_t)MTOT * HEAD;       // MTOT*64 bf16 (K)
    unsigned short* vt = kg + (size_t)MTOT * HEAD;       // [NB][HEAD][SEQ] bf16 (V^T)

    wt_kernel<<<dim3(768), dim3(256), 0, stream>>>(Wq, Wk, Wv, Wt);
    proj_kernel<<<dim3(MTOT / 32), dim3(256), 0, stream>>>(x, Wt, bq, bk, bv, qg, kg, vt);
    attn_kernel<<<dim3(SEQ / 32, NB), dim3(512), 0, stream>>>(qg, kg, vt, (float*)d_out);
}

// Round 4
// 97.220 us; speedup vs baseline: 2.0318x; 2.0318x over previous
//
#include <hip/hip_runtime.h>
#include <hip/hip_bf16.h>
#include <math.h>

#define EMB 1024
#define HEAD 64
#define NB 4
#define SEQ 4096
#define MTOT (NB * SEQ)
// fold 1/sqrt(64) and log2(e) into Q so softmax runs in base-2 (v_exp_f32 native)
#define QSCALE (0.125f * 1.44269504088896f)

typedef __attribute__((ext_vector_type(8))) short bf16x8;
typedef __attribute__((ext_vector_type(4))) float f32x4;

static __device__ __forceinline__ unsigned short f2b(float f) {
    union { float f; unsigned u; } v; v.f = f;
    unsigned r = v.u + 0x7FFFu + ((v.u >> 16) & 1u);
    return (unsigned short)(r >> 16);
}
static __device__ __forceinline__ float b2f(unsigned short u) {
    union { unsigned u; float f; } v; v.u = ((unsigned)u) << 16; return v.f;
}
// packed f32x2 -> bf16x2 (RTNE), one instruction
static __device__ __forceinline__ unsigned pk2(float lo, float hi) {
    unsigned r;
    asm("v_cvt_pk_bf16_f32 %0, %1, %2" : "=v"(r) : "v"(lo), "v"(hi));
    return r;
}

// ---------------------------------------------------------------------------
// Kernel 1: W transpose + bf16 cast.  Wt layout: [3][64 n][1024 k]
// ---------------------------------------------------------------------------
__global__ void wt_kernel(const float* __restrict__ Wq, const float* __restrict__ Wk,
                          const float* __restrict__ Wv, unsigned short* __restrict__ Wt) {
    const int idx = blockIdx.x * 256 + threadIdx.x;   // 3*64*1024 = 196608
    const int m = idx >> 16;
    const int r = idx & 65535;
    const int n = r >> 10, k = r & 1023;
    const float* W = (m == 0) ? Wq : (m == 1) ? Wk : Wv;
    Wt[idx] = f2b(W[k * HEAD + n]);
}

// ---------------------------------------------------------------------------
// Kernel 2: fused QKV projection (x read ONCE). grid MTOT/64, 256 threads.
// C = x[64 x 1024] @ W[1024 x 192] + bias.  N-frags 0-3: Q (pre-scaled),
// 4-7: K (row-major), 8-11: V written TRANSPOSED vt[b][h][s].
// (R2 version — measured ~24 us; R3 barrier-free variant regressed.)
// ---------------------------------------------------------------------------
__global__ __launch_bounds__(256) void proj_kernel(
    const float* __restrict__ x, const unsigned short* __restrict__ Wt3,
    const float* __restrict__ bq, const float* __restrict__ bk,
    const float* __restrict__ bv, unsigned short* __restrict__ qg,
    unsigned short* __restrict__ kg, unsigned short* __restrict__ vt) {
    __shared__ unsigned short Ax[64][72];    // +8 pad
    __shared__ unsigned short Wl[192][72];

    const int tid = threadIdx.x;
    const int wave = tid >> 6, lane = tid & 63;
    const int li = lane & 15, lg = lane >> 4;
    const int rbase = blockIdx.x * 64;

    f32x4 acc[12];
#pragma unroll
    for (int n = 0; n < 12; ++n) acc[n] = (f32x4){0.f, 0.f, 0.f, 0.f};

    const int xr = tid >> 2, xc = (tid & 3) * 16;

    for (int k0 = 0; k0 < EMB; k0 += 64) {
        __syncthreads();
        // stage x tile [64][64] fp32 -> bf16
        const float* xp = x + (size_t)(rbase + xr) * EMB + k0 + xc;
        float xv[16];
#pragma unroll
        for (int i = 0; i < 16; i += 4) {
            const float4 t = *(const float4*)(xp + i);
            xv[i] = t.x; xv[i + 1] = t.y; xv[i + 2] = t.z; xv[i + 3] = t.w;
        }
        union { bf16x8 v; unsigned u[4]; } pa, pb;
#pragma unroll
        for (int i = 0; i < 4; ++i) {
            pa.u[i] = pk2(xv[2 * i], xv[2 * i + 1]);
            pb.u[i] = pk2(xv[8 + 2 * i], xv[9 + 2 * i]);
        }
        *(bf16x8*)&Ax[xr][xc] = pa.v;
        *(bf16x8*)&Ax[xr][xc + 8] = pb.v;
        // stage W tile [192][64]
#pragma unroll
        for (int i = 0; i < 6; ++i) {
            const int chunk = tid + 256 * i;
            const int row = chunk >> 3, c8 = (chunk & 7) * 8;
            *(bf16x8*)&Wl[row][c8] = *(const bf16x8*)(Wt3 + (size_t)row * EMB + k0 + c8);
        }
        __syncthreads();

        const bf16x8 a0 = *(const bf16x8*)&Ax[wave * 16 + li][lg * 8];
        const bf16x8 a1 = *(const bf16x8*)&Ax[wave * 16 + li][32 + lg * 8];
#pragma unroll
        for (int n = 0; n < 12; ++n) {
            const bf16x8 b0 = *(const bf16x8*)&Wl[n * 16 + li][lg * 8];
            const bf16x8 b1 = *(const bf16x8*)&Wl[n * 16 + li][32 + lg * 8];
            acc[n] = __builtin_amdgcn_mfma_f32_16x16x32_bf16(a0, b0, acc[n], 0, 0, 0);
            acc[n] = __builtin_amdgcn_mfma_f32_16x16x32_bf16(a1, b1, acc[n], 0, 0, 0);
        }
    }
    // epilogue
#pragma unroll
    for (int n = 0; n < 12; ++n) {
        const int mat = n >> 2;
        const int nc = (n & 3) * 16 + li;
        const float bb = (mat == 0) ? bq[nc] : (mat == 1) ? bk[nc] : bv[nc];
#pragma unroll
        for (int r = 0; r < 4; ++r) {
            const int grow = rbase + wave * 16 + lg * 4 + r;
            const float val = acc[n][r] + bb;
            if (mat == 0) {
                qg[(size_t)grow * HEAD + nc] = f2b(val * QSCALE);
            } else if (mat == 1) {
                kg[(size_t)grow * HEAD + nc] = f2b(val);
            } else {
                const int bi = grow >> 12, si = grow & 4095;
                vt[((size_t)bi * HEAD + nc) * SEQ + si] = f2b(val);
            }
        }
    }
}

// ---------------------------------------------------------------------------
// Kernel 3: flash attention (causal). grid (128, NB) x 512 threads = 8 waves.
// Block bx owns q-tile (127-bx) -> longest blocks dispatch first.
// Wave w takes KV tiles t = w, w+8, ... (KVBLK=64). V loads issued after
// QK^T (latency hidden under softmax), halving peak live VGPRs vs R3.
// No forced occupancy: launch_bounds(512) only (R3's (512,4) caused spills).
// ---------------------------------------------------------------------------
__global__ __launch_bounds__(512) void attn_kernel(
    const unsigned short* __restrict__ Qg, const unsigned short* __restrict__ Kg,
    const unsigned short* __restrict__ Vtg, float* __restrict__ out) {
    // per-wave 4608B: P tile [2][16][72] during loop, O-partial [32][72] after.
    __shared__ unsigned short U[8][2304];
    __shared__ float ml[8][32][2];

    const int tid = threadIdx.x, w = tid >> 6, lane = tid & 63;
    const int li = lane & 15, lg = lane >> 4;
    const int b = blockIdx.y;
    const int qa0 = (gridDim.x - 1 - blockIdx.x) * 32;   // big tiles first
    const size_t qb = (size_t)b * SEQ * HEAD;
    const unsigned short* vb = Vtg + (size_t)b * HEAD * SEQ;

    const bf16x8 qf00 = *(const bf16x8*)(Qg + qb + (size_t)(qa0 + li) * HEAD + lg * 8);
    const bf16x8 qf01 = *(const bf16x8*)(Qg + qb + (size_t)(qa0 + li) * HEAD + 32 + lg * 8);
    const bf16x8 qf10 = *(const bf16x8*)(Qg + qb + (size_t)(qa0 + 16 + li) * HEAD + lg * 8);
    const bf16x8 qf11 = *(const bf16x8*)(Qg + qb + (size_t)(qa0 + 16 + li) * HEAD + 32 + lg * 8);

    f32x4 oa[2][4];
    float mS[2][4], lS[2][4];
#pragma unroll
    for (int q = 0; q < 2; ++q)
#pragma unroll
        for (int n = 0; n < 4; ++n) oa[q][n] = (f32x4){0.f, 0.f, 0.f, 0.f};
#pragma unroll
    for (int q = 0; q < 2; ++q)
#pragma unroll
        for (int r = 0; r < 4; ++r) { mS[q][r] = -1e30f; lS[q][r] = 0.f; }

    unsigned short* Pw = U[w];
    const int ntiles = (qa0 + 95) >> 6;            // ceil((qa0+32)/64)

    for (int t = w; t < ntiles; t += 8) {
        const int kv0 = t * 64;
        // ---- K fragments ----
        bf16x8 kf[4][2];
#pragma unroll
        for (int n = 0; n < 4; ++n) {
            const unsigned short* kp = Kg + qb + (size_t)(kv0 + n * 16 + li) * HEAD + lg * 8;
            kf[n][0] = *(const bf16x8*)kp;
            kf[n][1] = *(const bf16x8*)(kp + 32);
        }
        // ---- S = Q K^T ----
        f32x4 s[2][4];
#pragma unroll
        for (int n = 0; n < 4; ++n) {
            f32x4 z0 = (f32x4){0.f, 0.f, 0.f, 0.f};
            f32x4 z1 = (f32x4){0.f, 0.f, 0.f, 0.f};
            z0 = __builtin_amdgcn_mfma_f32_16x16x32_bf16(qf00, kf[n][0], z0, 0, 0, 0);
            s[0][n] = __builtin_amdgcn_mfma_f32_16x16x32_bf16(qf01, kf[n][1], z0, 0, 0, 0);
            z1 = __builtin_amdgcn_mfma_f32_16x16x32_bf16(qf10, kf[n][0], z1, 0, 0, 0);
            s[1][n] = __builtin_amdgcn_mfma_f32_16x16x32_bf16(qf11, kf[n][1], z1, 0, 0, 0);
        }
        // ---- V fragments (latency hidden under softmax) ----
        bf16x8 vf[4][2];
#pragma unroll
        for (int n = 0; n < 4; ++n) {
            const unsigned short* vp = vb + (size_t)(n * 16 + li) * SEQ + kv0 + lg * 8;
            vf[n][0] = *(const bf16x8*)vp;
            vf[n][1] = *(const bf16x8*)(vp + 32);
        }
        // ---- causal mask (only the diagonal-straddling tile) ----
        if (kv0 + 63 > qa0) {
#pragma unroll
            for (int n = 0; n < 4; ++n) {
                const int kv = kv0 + n * 16 + li;
#pragma unroll
                for (int q = 0; q < 2; ++q) {
                    const int qq = qa0 + q * 16 + lg * 4;
#pragma unroll
                    for (int r = 0; r < 4; ++r)
                        if (kv > qq + r) s[q][n][r] = -1e30f;
                }
            }
        }
        // ---- online softmax (base-2); per-lane partial l, defer-max ----
#pragma unroll
        for (int q = 0; q < 2; ++q) {
            float cm[4];
#pragma unroll
            for (int r = 0; r < 4; ++r)
                cm[r] = fmaxf(fmaxf(fmaxf(s[q][0][r], s[q][1][r]), s[q][2][r]), s[q][3][r]);
#pragma unroll
            for (int off = 1; off < 16; off <<= 1)
#pragma unroll
                for (int r = 0; r < 4; ++r)
                    cm[r] = fmaxf(cm[r], __shfl_xor(cm[r], off));
            float d = -1e30f;
#pragma unroll
            for (int r = 0; r < 4; ++r) d = fmaxf(d, cm[r] - mS[q][r]);
            if (!__all(d <= 8.0f)) {
#pragma unroll
                for (int r = 0; r < 4; ++r) {
                    const float mn = fmaxf(mS[q][r], cm[r]);
                    const float sc = exp2f(mS[q][r] - mn);
                    mS[q][r] = mn;
                    lS[q][r] *= sc;
#pragma unroll
                    for (int n = 0; n < 4; ++n) oa[q][n][r] *= sc;
                }
            }
#pragma unroll
            for (int n = 0; n < 4; ++n)
#pragma unroll
                for (int r = 0; r < 4; ++r) {
                    const float p = exp2f(s[q][n][r] - mS[q][r]);
                    s[q][n][r] = p;
                    lS[q][r] += p;
                }
            // P -> wave-local LDS (packed bf16 cvt)
#pragma unroll
            for (int n = 0; n < 4; ++n) {
                const unsigned u01 = pk2(s[q][n][0], s[q][n][1]);
                const unsigned u23 = pk2(s[q][n][2], s[q][n][3]);
                unsigned short* pp = &Pw[q * 1152 + (lg * 4) * 72 + n * 16 + li];
                pp[0] = (unsigned short)u01;
                pp[72] = (unsigned short)(u01 >> 16);
                pp[144] = (unsigned short)u23;
                pp[216] = (unsigned short)(u23 >> 16);
            }
        }
        // ---- PV ----
#pragma unroll
        for (int q = 0; q < 2; ++q) {
            const bf16x8 pf0 = *(const bf16x8*)&Pw[q * 1152 + li * 72 + lg * 8];
            const bf16x8 pf1 = *(const bf16x8*)&Pw[q * 1152 + li * 72 + 32 + lg * 8];
#pragma unroll
            for (int n = 0; n < 4; ++n) {
                oa[q][n] = __builtin_amdgcn_mfma_f32_16x16x32_bf16(pf0, vf[n][0], oa[q][n], 0, 0, 0);
                oa[q][n] = __builtin_amdgcn_mfma_f32_16x16x32_bf16(pf1, vf[n][1], oa[q][n], 0, 0, 0);
            }
        }
    }

    // reduce per-lane l partials across the 16-lane row groups (once)
#pragma unroll
    for (int off = 1; off < 16; off <<= 1)
#pragma unroll
        for (int q = 0; q < 2; ++q)
#pragma unroll
            for (int r = 0; r < 4; ++r)
                lS[q][r] += __shfl_xor(lS[q][r], off);

    // publish partials: O (bf16, reuse Pw region) + (m,l)
#pragma unroll
    for (int q = 0; q < 2; ++q)
#pragma unroll
        for (int n = 0; n < 4; ++n)
#pragma unroll
            for (int r = 0; r < 4; ++r)
                Pw[(q * 16 + lg * 4 + r) * 72 + n * 16 + li] = f2b(oa[q][n][r]);
    if (li == 0) {
#pragma unroll
        for (int q = 0; q < 2; ++q)
#pragma unroll
            for (int r = 0; r < 4; ++r) {
                ml[w][q * 16 + lg * 4 + r][0] = mS[q][r];
                ml[w][q * 16 + lg * 4 + r][1] = lS[q][r];
            }
    }
    __syncthreads();

    // merge 8 partials; wave w handles rows w*4..w*4+3, col = lane
#pragma unroll
    for (int rr = 0; rr < 4; ++rr) {
        const int row = w * 4 + rr;
        float ms = -1e30f;
#pragma unroll
        for (int j = 0; j < 8; ++j) ms = fmaxf(ms, ml[j][row][0]);
        float ls = 0.f, o = 0.f;
#pragma unroll
        for (int j = 0; j < 8; ++j) {
            const float c = exp2f(ml[j][row][0] - ms);
            ls += c * ml[j][row][1];
            o += c * b2f(U[j][row * 72 + lane]);
        }
        out[((size_t)b * SEQ + qa0 + row) * HEAD + lane] = o / ls;
    }
}

// ---------------------------------------------------------------------------
extern "C" void kernel_launch(void* const* d_in, const int* in_sizes, int n_in,
                              void* d_out, int out_size, void* d_ws, size_t ws_size,
                              hipStream_t stream) {
    const float* x  = (const float*)d_in[0];
    const float* Wq = (const float*)d_in[1];
    const float* bq = (const float*)d_in[2];
    const float* Wk = (const float*)d_in[3];
    const float* bk = (const float*)d_in[4];
    const float* Wv = (const float*)d_in[5];
    const float* bv = (const float*)d_in[6];

    unsigned short* Wt = (unsigned short*)d_ws;          // 3*64*1024
    unsigned short* qg = Wt + 3 * HEAD * EMB;            // MTOT*64 bf16 (Q, pre-scaled)
    unsigned short* kg = qg + (size_t)MTOT * HEAD;       // MTOT*64 bf16 (K)
    unsigned short* vt = kg + (size_t)MTOT * HEAD;       // [NB][HEAD][SEQ] bf16 (V^T)

    wt_kernel<<<dim3(768), dim3(256), 0, stream>>>(Wq, Wk, Wv, Wt);
    proj_kernel<<<dim3(MTOT / 64), dim3(256), 0, stream>>>(x, Wt, bq, bk, bv, qg, kg, vt);
    attn_kernel<<<dim3(SEQ / 32, NB), dim3(512), 0, stream>>>(qg, kg, vt, (float*)d_out);
}

// Round 5
// 93.779 us; speedup vs baseline: 2.1064x; 1.0367x over previous
//
#include <hip/hip_runtime.h>
#include <hip/hip_bf16.h>
#include <math.h>

#define EMB 1024
#define HEAD 64
#define NB 4
#define SEQ 4096
#define MTOT (NB * SEQ)
// fold 1/sqrt(64) and log2(e) into Q so softmax runs in base-2 (v_exp_f32 native)
#define QSCALE (0.125f * 1.44269504088896f)

typedef __attribute__((ext_vector_type(8))) short bf16x8;
typedef __attribute__((ext_vector_type(4))) float f32x4;

static __device__ __forceinline__ unsigned short f2b(float f) {
    union { float f; unsigned u; } v; v.f = f;
    unsigned r = v.u + 0x7FFFu + ((v.u >> 16) & 1u);
    return (unsigned short)(r >> 16);
}
static __device__ __forceinline__ float b2f(unsigned short u) {
    union { unsigned u; float f; } v; v.u = ((unsigned)u) << 16; return v.f;
}
// packed f32x2 -> bf16x2 (RTNE), one instruction
static __device__ __forceinline__ unsigned pk2(float lo, float hi) {
    unsigned r;
    asm("v_cvt_pk_bf16_f32 %0, %1, %2" : "=v"(r) : "v"(lo), "v"(hi));
    return r;
}

// ---------------------------------------------------------------------------
// Kernel 1: W transpose + bf16 cast.  Wt layout: [3][64 n][1024 k]
// ---------------------------------------------------------------------------
__global__ void wt_kernel(const float* __restrict__ Wq, const float* __restrict__ Wk,
                          const float* __restrict__ Wv, unsigned short* __restrict__ Wt) {
    const int idx = blockIdx.x * 256 + threadIdx.x;   // 3*64*1024 = 196608
    const int m = idx >> 16;
    const int r = idx & 65535;
    const int n = r >> 10, k = r & 1023;
    const float* W = (m == 0) ? Wq : (m == 1) ? Wk : Wv;
    Wt[idx] = f2b(W[k * HEAD + n]);
}

// ---------------------------------------------------------------------------
// Kernel 2: fused QKV projection (x read ONCE). grid MTOT/64, 256 threads.
// (R2 version — measured ~24 us total with wt; attack next round w/ counters.)
// ---------------------------------------------------------------------------
__global__ __launch_bounds__(256) void proj_kernel(
    const float* __restrict__ x, const unsigned short* __restrict__ Wt3,
    const float* __restrict__ bq, const float* __restrict__ bk,
    const float* __restrict__ bv, unsigned short* __restrict__ qg,
    unsigned short* __restrict__ kg, unsigned short* __restrict__ vt) {
    __shared__ unsigned short Ax[64][72];    // +8 pad
    __shared__ unsigned short Wl[192][72];

    const int tid = threadIdx.x;
    const int wave = tid >> 6, lane = tid & 63;
    const int li = lane & 15, lg = lane >> 4;
    const int rbase = blockIdx.x * 64;

    f32x4 acc[12];
#pragma unroll
    for (int n = 0; n < 12; ++n) acc[n] = (f32x4){0.f, 0.f, 0.f, 0.f};

    const int xr = tid >> 2, xc = (tid & 3) * 16;

    for (int k0 = 0; k0 < EMB; k0 += 64) {
        __syncthreads();
        const float* xp = x + (size_t)(rbase + xr) * EMB + k0 + xc;
        float xv[16];
#pragma unroll
        for (int i = 0; i < 16; i += 4) {
            const float4 t = *(const float4*)(xp + i);
            xv[i] = t.x; xv[i + 1] = t.y; xv[i + 2] = t.z; xv[i + 3] = t.w;
        }
        union { bf16x8 v; unsigned u[4]; } pa, pb;
#pragma unroll
        for (int i = 0; i < 4; ++i) {
            pa.u[i] = pk2(xv[2 * i], xv[2 * i + 1]);
            pb.u[i] = pk2(xv[8 + 2 * i], xv[9 + 2 * i]);
        }
        *(bf16x8*)&Ax[xr][xc] = pa.v;
        *(bf16x8*)&Ax[xr][xc + 8] = pb.v;
#pragma unroll
        for (int i = 0; i < 6; ++i) {
            const int chunk = tid + 256 * i;
            const int row = chunk >> 3, c8 = (chunk & 7) * 8;
            *(bf16x8*)&Wl[row][c8] = *(const bf16x8*)(Wt3 + (size_t)row * EMB + k0 + c8);
        }
        __syncthreads();

        const bf16x8 a0 = *(const bf16x8*)&Ax[wave * 16 + li][lg * 8];
        const bf16x8 a1 = *(const bf16x8*)&Ax[wave * 16 + li][32 + lg * 8];
#pragma unroll
        for (int n = 0; n < 12; ++n) {
            const bf16x8 b0 = *(const bf16x8*)&Wl[n * 16 + li][lg * 8];
            const bf16x8 b1 = *(const bf16x8*)&Wl[n * 16 + li][32 + lg * 8];
            acc[n] = __builtin_amdgcn_mfma_f32_16x16x32_bf16(a0, b0, acc[n], 0, 0, 0);
            acc[n] = __builtin_amdgcn_mfma_f32_16x16x32_bf16(a1, b1, acc[n], 0, 0, 0);
        }
    }
#pragma unroll
    for (int n = 0; n < 12; ++n) {
        const int mat = n >> 2;
        const int nc = (n & 3) * 16 + li;
        const float bb = (mat == 0) ? bq[nc] : (mat == 1) ? bk[nc] : bv[nc];
#pragma unroll
        for (int r = 0; r < 4; ++r) {
            const int grow = rbase + wave * 16 + lg * 4 + r;
            const float val = acc[n][r] + bb;
            if (mat == 0) {
                qg[(size_t)grow * HEAD + nc] = f2b(val * QSCALE);
            } else if (mat == 1) {
                kg[(size_t)grow * HEAD + nc] = f2b(val);
            } else {
                const int bi = grow >> 12, si = grow & 4095;
                vt[((size_t)bi * HEAD + nc) * SEQ + si] = f2b(val);
            }
        }
    }
}

// ---------------------------------------------------------------------------
// Kernel 3: flash attention, flat (b, qtile32, kv-window) work units — one
// independent wave each, NO barriers. Wave processes tiles [W*k, W*k+W) of
// its q-tile (KVBLK=64 each), writes (m,l) fp32 + O bf16 partial to ws.
// Window flat-index decode: segment k holds q-tiles qidx >= 2*W*k
// (count 128-2Wk, offset Ok = 128k - W*k*(k-1)).
// ---------------------------------------------------------------------------
template<int W, int NWIN, int KMAX>
__global__ __launch_bounds__(256) void attn_kernel(
    const unsigned short* __restrict__ Qg, const unsigned short* __restrict__ Kg,
    const unsigned short* __restrict__ Vtg, unsigned short* __restrict__ pO,
    float* __restrict__ pML) {
    __shared__ unsigned short U[4][2304];   // per-wave P transpose tile [2][16][72]

    const int tid = threadIdx.x, lane = tid & 63;
    const int li = lane & 15, lg = lane >> 4;
    const int b = blockIdx.y;
    const int w = blockIdx.x * 4 + (tid >> 6);
    // decode (qidx, win)
    int k = 0;
#pragma unroll
    for (int kk = 1; kk < KMAX; ++kk) {
        const int Ok = 128 * kk - W * kk * (kk - 1);
        if (w >= Ok) k = kk;
    }
    const int Ok = 128 * k - W * k * (k - 1);
    const int qidx = 2 * W * k + (w - Ok);
    const int qa0 = qidx * 32;
    const int ntiles = (qa0 + 95) >> 6;
    const int t0 = W * k;
    const int tend = min(t0 + W, ntiles);

    const size_t qb = (size_t)b * SEQ * HEAD;
    const unsigned short* vb = Vtg + (size_t)b * HEAD * SEQ;

    const bf16x8 qf00 = *(const bf16x8*)(Qg + qb + (size_t)(qa0 + li) * HEAD + lg * 8);
    const bf16x8 qf01 = *(const bf16x8*)(Qg + qb + (size_t)(qa0 + li) * HEAD + 32 + lg * 8);
    const bf16x8 qf10 = *(const bf16x8*)(Qg + qb + (size_t)(qa0 + 16 + li) * HEAD + lg * 8);
    const bf16x8 qf11 = *(const bf16x8*)(Qg + qb + (size_t)(qa0 + 16 + li) * HEAD + 32 + lg * 8);

    f32x4 oa[2][4];
    float mS[2][4], lS[2][4];
#pragma unroll
    for (int q = 0; q < 2; ++q)
#pragma unroll
        for (int n = 0; n < 4; ++n) oa[q][n] = (f32x4){0.f, 0.f, 0.f, 0.f};
#pragma unroll
    for (int q = 0; q < 2; ++q)
#pragma unroll
        for (int r = 0; r < 4; ++r) { mS[q][r] = -1e30f; lS[q][r] = 0.f; }

    unsigned short* Pw = U[tid >> 6];

    for (int t = t0; t < tend; ++t) {
        const int kv0 = t * 64;
        // ---- K fragments ----
        bf16x8 kf[4][2];
#pragma unroll
        for (int n = 0; n < 4; ++n) {
            const unsigned short* kp = Kg + qb + (size_t)(kv0 + n * 16 + li) * HEAD + lg * 8;
            kf[n][0] = *(const bf16x8*)kp;
            kf[n][1] = *(const bf16x8*)(kp + 32);
        }
        // ---- S = Q K^T ----
        f32x4 s[2][4];
#pragma unroll
        for (int n = 0; n < 4; ++n) {
            f32x4 z0 = (f32x4){0.f, 0.f, 0.f, 0.f};
            f32x4 z1 = (f32x4){0.f, 0.f, 0.f, 0.f};
            z0 = __builtin_amdgcn_mfma_f32_16x16x32_bf16(qf00, kf[n][0], z0, 0, 0, 0);
            s[0][n] = __builtin_amdgcn_mfma_f32_16x16x32_bf16(qf01, kf[n][1], z0, 0, 0, 0);
            z1 = __builtin_amdgcn_mfma_f32_16x16x32_bf16(qf10, kf[n][0], z1, 0, 0, 0);
            s[1][n] = __builtin_amdgcn_mfma_f32_16x16x32_bf16(qf11, kf[n][1], z1, 0, 0, 0);
        }
        // ---- V fragments (latency hidden under softmax) ----
        bf16x8 vf[4][2];
#pragma unroll
        for (int n = 0; n < 4; ++n) {
            const unsigned short* vp = vb + (size_t)(n * 16 + li) * SEQ + kv0 + lg * 8;
            vf[n][0] = *(const bf16x8*)vp;
            vf[n][1] = *(const bf16x8*)(vp + 32);
        }
        // ---- causal mask: only the last tile of this q-tile straddles ----
        if (t == ntiles - 1) {
#pragma unroll
            for (int n = 0; n < 4; ++n) {
                const int kv = kv0 + n * 16 + li;
#pragma unroll
                for (int q = 0; q < 2; ++q) {
                    const int qq = qa0 + q * 16 + lg * 4;
#pragma unroll
                    for (int r = 0; r < 4; ++r)
                        if (kv > qq + r) s[q][n][r] = -1e30f;
                }
            }
        }
        // ---- online softmax (base-2); per-lane partial l, defer-max ----
#pragma unroll
        for (int q = 0; q < 2; ++q) {
            float cm[4];
#pragma unroll
            for (int r = 0; r < 4; ++r)
                cm[r] = fmaxf(fmaxf(fmaxf(s[q][0][r], s[q][1][r]), s[q][2][r]), s[q][3][r]);
#pragma unroll
            for (int off = 1; off < 16; off <<= 1)
#pragma unroll
                for (int r = 0; r < 4; ++r)
                    cm[r] = fmaxf(cm[r], __shfl_xor(cm[r], off));
            float d = -1e30f;
#pragma unroll
            for (int r = 0; r < 4; ++r) d = fmaxf(d, cm[r] - mS[q][r]);
            if (!__all(d <= 8.0f)) {
#pragma unroll
                for (int r = 0; r < 4; ++r) {
                    const float mn = fmaxf(mS[q][r], cm[r]);
                    const float sc = exp2f(mS[q][r] - mn);
                    mS[q][r] = mn;
                    lS[q][r] *= sc;
#pragma unroll
                    for (int n = 0; n < 4; ++n) oa[q][n][r] *= sc;
                }
            }
#pragma unroll
            for (int n = 0; n < 4; ++n)
#pragma unroll
                for (int r = 0; r < 4; ++r) {
                    const float p = exp2f(s[q][n][r] - mS[q][r]);
                    s[q][n][r] = p;
                    lS[q][r] += p;
                }
            // P -> wave-local LDS (packed bf16 cvt)
#pragma unroll
            for (int n = 0; n < 4; ++n) {
                const unsigned u01 = pk2(s[q][n][0], s[q][n][1]);
                const unsigned u23 = pk2(s[q][n][2], s[q][n][3]);
                unsigned short* pp = &Pw[q * 1152 + (lg * 4) * 72 + n * 16 + li];
                pp[0] = (unsigned short)u01;
                pp[72] = (unsigned short)(u01 >> 16);
                pp[144] = (unsigned short)u23;
                pp[216] = (unsigned short)(u23 >> 16);
            }
        }
        // ---- PV ----
#pragma unroll
        for (int q = 0; q < 2; ++q) {
            const bf16x8 pf0 = *(const bf16x8*)&Pw[q * 1152 + li * 72 + lg * 8];
            const bf16x8 pf1 = *(const bf16x8*)&Pw[q * 1152 + li * 72 + 32 + lg * 8];
#pragma unroll
            for (int n = 0; n < 4; ++n) {
                oa[q][n] = __builtin_amdgcn_mfma_f32_16x16x32_bf16(pf0, vf[n][0], oa[q][n], 0, 0, 0);
                oa[q][n] = __builtin_amdgcn_mfma_f32_16x16x32_bf16(pf1, vf[n][1], oa[q][n], 0, 0, 0);
            }
        }
    }

    // reduce per-lane l partials across the 16-lane row groups (once)
#pragma unroll
    for (int off = 1; off < 16; off <<= 1)
#pragma unroll
        for (int q = 0; q < 2; ++q)
#pragma unroll
            for (int r = 0; r < 4; ++r)
                lS[q][r] += __shfl_xor(lS[q][r], off);

    // write partial: O bf16 [32][64] + ml fp32 [32][2]
    const size_t gw = (size_t)b * NWIN + w;
    unsigned short* po = pO + gw * 2048;
#pragma unroll
    for (int q = 0; q < 2; ++q)
#pragma unroll
        for (int n = 0; n < 4; ++n)
#pragma unroll
            for (int r = 0; r < 4; ++r)
                po[(q * 16 + lg * 4 + r) * 64 + n * 16 + li] = f2b(oa[q][n][r]);
    if (li == 0) {
        float* pml = pML + gw * 64;
#pragma unroll
        for (int q = 0; q < 2; ++q)
#pragma unroll
            for (int r = 0; r < 4; ++r) {
                const int row = q * 16 + lg * 4 + r;
                pml[row * 2] = mS[q][r];
                pml[row * 2 + 1] = lS[q][r];
            }
    }
}

// ---------------------------------------------------------------------------
// Kernel 4: merge <= KMAX window-partials per q-tile. grid (128, NB), 256 thr.
// Thread handles (row = tid/8, 8 cols). Two-pass over pML (no runtime arrays).
// ---------------------------------------------------------------------------
template<int W, int NWIN, int KMAX>
__global__ __launch_bounds__(256) void merge_kernel(
    const unsigned short* __restrict__ pO, const float* __restrict__ pML,
    float* __restrict__ out) {
    const int qidx = blockIdx.x, b = blockIdx.y;
    const int qa0 = qidx * 32;
    const int ntiles = (qa0 + 95) >> 6;
    const int wcount = (ntiles + W - 1) / W;
    const int t = threadIdx.x;
    const int row = t >> 3, c8 = (t & 7) * 8;

    float M = -1e30f;
    for (int k = 0; k < wcount; ++k) {
        const int Ok = 128 * k - W * k * (k - 1);
        const size_t gw = (size_t)b * NWIN + Ok + (qidx - 2 * W * k);
        M = fmaxf(M, pML[gw * 64 + row * 2]);
    }
    float acc[8] = {0.f, 0.f, 0.f, 0.f, 0.f, 0.f, 0.f, 0.f};
    float L = 0.f;
    for (int k = 0; k < wcount; ++k) {
        const int Ok = 128 * k - W * k * (k - 1);
        const size_t gw = (size_t)b * NWIN + Ok + (qidx - 2 * W * k);
        const float mk = pML[gw * 64 + row * 2];
        const float lk = pML[gw * 64 + row * 2 + 1];
        const float wgt = exp2f(mk - M);
        L += wgt * lk;
        const bf16x8 o = *(const bf16x8*)&pO[gw * 2048 + (size_t)row * 64 + c8];
#pragma unroll
        for (int i = 0; i < 8; ++i) acc[i] += wgt * b2f((unsigned short)o[i]);
    }
    const float inv = 1.0f / L;
    float* op = out + ((size_t)b * SEQ + qa0 + row) * HEAD + c8;
#pragma unroll
    for (int i = 0; i < 8; ++i) op[i] = acc[i] * inv;
}

// ---------------------------------------------------------------------------
extern "C" void kernel_launch(void* const* d_in, const int* in_sizes, int n_in,
                              void* d_out, int out_size, void* d_ws, size_t ws_size,
                              hipStream_t stream) {
    const float* x  = (const float*)d_in[0];
    const float* Wq = (const float*)d_in[1];
    const float* bq = (const float*)d_in[2];
    const float* Wk = (const float*)d_in[3];
    const float* bk = (const float*)d_in[4];
    const float* Wv = (const float*)d_in[5];
    const float* bv = (const float*)d_in[6];

    unsigned short* Wt = (unsigned short*)d_ws;          // 3*64*1024
    unsigned short* qg = Wt + 3 * HEAD * EMB;            // MTOT*64 bf16 (Q, pre-scaled)
    unsigned short* kg = qg + (size_t)MTOT * HEAD;       // MTOT*64 bf16 (K)
    unsigned short* vt = kg + (size_t)MTOT * HEAD;       // [NB][HEAD][SEQ] bf16 (V^T)
    unsigned short* pO = vt + (size_t)MTOT * HEAD;       // window partials (bf16)

    wt_kernel<<<dim3(768), dim3(256), 0, stream>>>(Wq, Wk, Wv, Wt);
    proj_kernel<<<dim3(MTOT / 64), dim3(256), 0, stream>>>(x, Wt, bq, bk, bv, qg, kg, vt);

    const size_t base_shorts = (size_t)3 * HEAD * EMB + (size_t)3 * MTOT * HEAD;
    const size_t need4 = base_shorts * 2 + (size_t)NB * 1088 * (2048 * 2 + 64 * 4);
    if (ws_size >= need4) {
        // W=4: 4352 waves, 1088 blocks/batch-row — higher occupancy
        float* pML = (float*)(pO + (size_t)NB * 1088 * 2048);
        attn_kernel<4, 1088, 16><<<dim3(1088 / 4, NB), dim3(256), 0, stream>>>(qg, kg, vt, pO, pML);
        merge_kernel<4, 1088, 16><<<dim3(128, NB), dim3(256), 0, stream>>>(pO, pML, (float*)d_out);
    } else {
        // W=8: fits in ~16.7 MB of ws
        float* pML = (float*)(pO + (size_t)NB * 576 * 2048);
        attn_kernel<8, 576, 8><<<dim3(576 / 4, NB), dim3(256), 0, stream>>>(qg, kg, vt, pO, pML);
        merge_kernel<8, 576, 8><<<dim3(128, NB), dim3(256), 0, stream>>>(pO, pML, (float*)d_out);
    }
}